// Round 6
// baseline (507.936 us; speedup 1.0000x reference)
//
#include <hip/hip_runtime.h>
#include <hip/hip_bf16.h>

// Problem constants (fixed by setup_inputs)
#define BB 16
#define NN 512
#define CC 128
#define HH 8
#define DHD 16
#define TT 8192      // B*N
#define EE 262144    // T*DEG
#define RWD 64

// ---------------------------------------------------------------------------
// Diagnostic fallback when ws_size is too small: out[0]=1000+ws_MB, rest 0.
__global__ void k_diag(float* __restrict__ out, int n, float code)
{
    int i = blockIdx.x*256 + threadIdx.x;
    if (i < n) out[i] = (i == 0) ? code : 0.f;
}

// ---------------------------------------------------------------------------
// w = silu(silu(ones@Wr0) @ Wr1/8) @ Wr2/8   (edge-independent: emb is all-1)
__global__ void k_compute_w(const float* __restrict__ Wr0, const float* __restrict__ Wr1,
                            const float* __restrict__ Wr2, float* __restrict__ w)
{
    __shared__ float h0[RWD], h1[RWD];
    int tid = threadIdx.x;
    if (tid < RWD) { float x = Wr0[tid]; h0[tid] = x / (1.f + __expf(-x)); }
    __syncthreads();
    if (tid < RWD) {
        float s = 0.f;
        for (int i = 0; i < RWD; i++) s += h0[i] * Wr1[i*RWD + tid];
        s *= 0.125f;
        h1[tid] = s / (1.f + __expf(-s));
    }
    __syncthreads();
    {
        float s = 0.f;
        for (int i = 0; i < RWD; i++) s += h1[i] * Wr2[i*2*CC + tid];
        w[tid] = s * 0.125f;
    }
}

// ---------------------------------------------------------------------------
// (T,128)@(128,128). MODE 0: row-major out.  MODE 1: scatter to (B,H,N,16).
template<int MODE>
__global__ __launch_bounds__(256) void k_gemm(const float* __restrict__ A,
                                              const float* __restrict__ Bw,
                                              const float* __restrict__ bias,
                                              float* __restrict__ out, float alpha)
{
    __shared__ float a_lds[128][36];   // A^T tile: [k][r]
    const int tid  = threadIdx.x;
    const int row0 = blockIdx.x * 32;

    for (int idx = tid; idx < 32*128; idx += 256) {
        int r = idx >> 7, k = idx & 127;
        a_lds[k][r] = A[(size_t)(row0 + r)*128 + k];
    }
    __syncthreads();

    const int c    = tid & 127;
    const int half = tid >> 7;
    float acc[16];
    #pragma unroll
    for (int i = 0; i < 16; i++) acc[i] = 0.f;

    const float* bp = Bw + c;
    for (int k = 0; k < 128; k++) {
        float b = bp[k*128];
        const float* ap = &a_lds[k][half*16];
        #pragma unroll
        for (int i = 0; i < 16; i++) acc[i] = fmaf(ap[i], b, acc[i]);
    }

    float bia = bias ? bias[c] : 0.f;
    #pragma unroll
    for (int i = 0; i < 16; i++) {
        int r = row0 + half*16 + i;
        float v = alpha * acc[i] + bia;
        if (MODE == 0) {
            out[(size_t)r*128 + c] = v;
        } else {
            int b_ = r >> 9, n_ = r & 511, h_ = c >> 4, d_ = c & 15;
            out[(((size_t)(b_*HH + h_)*NN + n_)*DHD) + d_] = v;
        }
    }
}

// ---------------------------------------------------------------------------
// Attention: one (b,h) per 2 blocks (256 query rows each). K/V tiles in LDS.
__global__ __launch_bounds__(256) void k_attn(const float* __restrict__ qb,
                                              const float* __restrict__ kb,
                                              const float* __restrict__ vb,
                                              float* __restrict__ attn)
{
    __shared__ float k_lds[512*16];
    __shared__ float v_lds[512*16];
    int bx = blockIdx.x;
    int bh = bx >> 1;
    int tile = bx & 1;
    const float* kp = kb + (size_t)bh * 512 * 16;
    const float* vp = vb + (size_t)bh * 512 * 16;
    for (int idx = threadIdx.x; idx < 8192; idx += 256) {
        k_lds[idx] = kp[idx];
        v_lds[idx] = vp[idx];
    }
    int n = tile*256 + threadIdx.x;
    float q[16];
    const float* qp = qb + ((size_t)bh*512 + n)*16;
    #pragma unroll
    for (int d = 0; d < 16; d++) q[d] = qp[d];
    __syncthreads();

    float m = -1e30f, l = 0.f, o[16];
    #pragma unroll
    for (int d = 0; d < 16; d++) o[d] = 0.f;

    for (int j0 = 0; j0 < 512; j0 += 16) {
        float s[16];
        float cmax = -1e30f;
        #pragma unroll
        for (int jj = 0; jj < 16; jj++) {
            const float* kr = &k_lds[(j0 + jj)*16];
            float a = 0.f;
            #pragma unroll
            for (int d = 0; d < 16; d++) a = fmaf(q[d], kr[d], a);
            s[jj] = a * 0.25f;               // 1/sqrt(16)
            cmax = fmaxf(cmax, s[jj]);
        }
        float mn = fmaxf(m, cmax);
        float scale = __expf(m - mn);
        l *= scale;
        #pragma unroll
        for (int d = 0; d < 16; d++) o[d] *= scale;
        #pragma unroll
        for (int jj = 0; jj < 16; jj++) {
            float p = __expf(s[jj] - mn);
            l += p;
            const float* vr = &v_lds[(j0 + jj)*16];
            #pragma unroll
            for (int d = 0; d < 16; d++) o[d] = fmaf(p, vr[d], o[d]);
        }
        m = mn;
    }
    int b_ = bh >> 3, h_ = bh & 7;
    float invl = 1.f / l;   // l >= 1 (max term contributes exp(0)=1)
    float* op = attn + ((size_t)(b_*512 + n))*128 + h_*16;
    #pragma unroll
    for (int d = 0; d < 16; d++) op[d] = q[d] + o[d]*invl;
}

// ---------------------------------------------------------------------------
// LayerNorm over last dim (128). 2 rows per block.
__global__ __launch_bounds__(256) void k_ln0(const float* __restrict__ in,
                                             const float* __restrict__ g0,
                                             const float* __restrict__ b0,
                                             float* __restrict__ out)
{
    int tid = threadIdx.x;
    int r = blockIdx.x*2 + (tid >> 7);
    int c = tid & 127;
    float v = in[(size_t)r*128 + c];
    float s1 = v, s2 = v*v;
    #pragma unroll
    for (int off = 32; off; off >>= 1) {
        s1 += __shfl_xor(s1, off);
        s2 += __shfl_xor(s2, off);
    }
    __shared__ float part[4][2];
    int wv = tid >> 6;
    if ((tid & 63) == 0) { part[wv][0] = s1; part[wv][1] = s2; }
    __syncthreads();
    int wp = (tid >> 7)*2;
    float a1 = part[wp][0] + part[wp+1][0];
    float a2 = part[wp][1] + part[wp+1][1];
    float mu = a1 * (1.f/128.f);
    float var = fmaxf(a2 * (1.f/128.f) - mu*mu, 0.f);
    out[(size_t)r*128 + c] = (v - mu)*rsqrtf(var + 1e-5f)*g0[c] + b0[c];
}

// ---------------------------------------------------------------------------
// Fused: y = o + relu(o@Wf + bf); inv = LN1(y)
__global__ __launch_bounds__(256) void k_ff_ln(const float* __restrict__ A,
                                               const float* __restrict__ Wf,
                                               const float* __restrict__ bfp,
                                               const float* __restrict__ g1,
                                               const float* __restrict__ b1,
                                               float* __restrict__ out)
{
    __shared__ float a_lds[128][36];
    __shared__ float y_lds[32][129];
    __shared__ float red[32][8][2];
    __shared__ float mu_s[32], rs_s[32];
    const int tid  = threadIdx.x;
    const int row0 = blockIdx.x * 32;

    for (int idx = tid; idx < 32*128; idx += 256) {
        int r = idx >> 7, k = idx & 127;
        a_lds[k][r] = A[(size_t)(row0 + r)*128 + k];
    }
    __syncthreads();

    const int c    = tid & 127;
    const int half = tid >> 7;
    float acc[16];
    #pragma unroll
    for (int i = 0; i < 16; i++) acc[i] = 0.f;
    const float* bp = Wf + c;
    for (int k = 0; k < 128; k++) {
        float b = bp[k*128];
        const float* ap = &a_lds[k][half*16];
        #pragma unroll
        for (int i = 0; i < 16; i++) acc[i] = fmaf(ap[i], b, acc[i]);
    }
    float bia = bfp[c];
    #pragma unroll
    for (int i = 0; i < 16; i++) {
        int rl = half*16 + i;
        float o = a_lds[c][rl];  // a_lds[k][r] holds A^T
        float rl_ = fmaxf(acc[i] + bia, 0.f);
        y_lds[rl][c] = o + rl_;
    }
    __syncthreads();
    int rr = tid >> 3, seg = tid & 7;
    float s1 = 0.f, s2 = 0.f;
    for (int c2 = seg*16; c2 < seg*16 + 16; c2++) {
        float v = y_lds[rr][c2];
        s1 += v; s2 += v*v;
    }
    red[rr][seg][0] = s1; red[rr][seg][1] = s2;
    __syncthreads();
    if (seg == 0) {
        float a1 = 0.f, a2 = 0.f;
        #pragma unroll
        for (int s = 0; s < 8; s++) { a1 += red[rr][s][0]; a2 += red[rr][s][1]; }
        float mu = a1 * (1.f/128.f);
        float var = fmaxf(a2 * (1.f/128.f) - mu*mu, 0.f);
        mu_s[rr] = mu; rs_s[rr] = rsqrtf(var + 1e-5f);
    }
    __syncthreads();
    float g = g1[c], bb = b1[c];
    #pragma unroll
    for (int i = 0; i < 16; i++) {
        int rl = half*16 + i;
        float v = y_lds[rl][c];
        out[(size_t)(row0 + rl)*128 + c] = (v - mu_s[rl])*rs_s[rl]*g + bb;
    }
}

// ---------------------------------------------------------------------------
// z[t][j] = sum_c x1[t][c]*Wz[c][j], Wz fused from W20/W21*w0/w1*scale.
__global__ __launch_bounds__(256) void k_z(const float* __restrict__ x1,
                                           const float* __restrict__ W20,
                                           const float* __restrict__ W21,
                                           const float* __restrict__ w,
                                           float* __restrict__ z)
{
    __shared__ float wz[128*16];
    __shared__ float xt[16*132];
    int tid = threadIdx.x;
    const float SCALE_Z = 0.027950849718747372f;  // 1/sqrt(128*10)
    for (int idx = tid; idx < 2048; idx += 256) {
        int c2 = idx >> 4, j = idx & 15;
        float base = (j < 8) ? W20[c2*8 + j] * w[c2]
                             : W21[c2*8 + (j-8)] * w[128 + c2];
        wz[idx] = base * SCALE_Z;
    }
    int row0 = blockIdx.x * 16;
    for (int idx = tid; idx < 2048; idx += 256) {
        int r = idx >> 7, c2 = idx & 127;
        xt[r*132 + c2] = x1[(size_t)(row0 + r)*128 + c2];
    }
    __syncthreads();
    int rl = tid >> 4, j = tid & 15;
    float acc = 0.f;
    for (int c2 = 0; c2 < 128; c2++) acc = fmaf(xt[rl*132 + c2], wz[c2*16 + j], acc);
    z[(size_t)(row0 + rl)*16 + j] = acc;
}

// ---------------------------------------------------------------------------
// eq init: eq[t][j] = (j<8) ? (X[t]@Wsc)[j]/sqrt(C) : 0.
__global__ __launch_bounds__(256) void k_xsc(const float* __restrict__ X,
                                             const float* __restrict__ Wsc,
                                             float* __restrict__ eq)
{
    __shared__ float wsl[128*8];
    __shared__ float xt[8*132];
    int tid = threadIdx.x;
    for (int idx = tid; idx < 1024; idx += 256) wsl[idx] = Wsc[idx] * 0.08838834764831845f;
    int row0 = blockIdx.x * 8;
    for (int idx = tid; idx < 1024; idx += 256) {
        int r = idx >> 7, c2 = idx & 127;
        xt[r*132 + c2] = X[(size_t)(row0 + r)*128 + c2];
    }
    __syncthreads();
    int rl = tid >> 5, j = tid & 31;
    float acc = 0.f;
    if (j < 8) {
        for (int c2 = 0; c2 < 128; c2++) acc = fmaf(xt[rl*132 + c2], wsl[c2*8 + j], acc);
    }
    eq[(size_t)(row0 + rl)*32 + j] = acc;
}

// ---------------------------------------------------------------------------
__global__ void k_y1(const float* __restrict__ ev, float* __restrict__ y1)
{
    int e = blockIdx.x*256 + threadIdx.x;
    if (e >= EE) return;
    float x = ev[e*3], y = ev[e*3+1], zz = ev[e*3+2];
    float nrm = sqrtf(x*x + y*y + zz*zz);
    float inv = 1.f / fmaxf(nrm, 1e-12f);
    const float s3 = 1.7320508075688772f;
    y1[e*3 + 0] = s3 * y  * inv;
    y1[e*3 + 1] = s3 * zz * inv;
    y1[e*3 + 2] = s3 * x  * inv;
}

// ---------------------------------------------------------------------------
__global__ void k_bucket(const int* __restrict__ ei, int* __restrict__ counts,
                         int* __restrict__ bucket)
{
    int e = blockIdx.x*256 + threadIdx.x;
    if (e >= EE) return;
    int t = ei[EE + e] & (TT-1);   // rcv (mask = no-op for valid data)
    int pos = atomicAdd(&counts[t], 1);
    if (pos < 128) bucket[(size_t)t*128 + pos] = e;
}

// ---------------------------------------------------------------------------
__global__ __launch_bounds__(256) void k_gather(const int* __restrict__ ei,
                                                const int* __restrict__ counts,
                                                const int* __restrict__ bucket,
                                                const float* __restrict__ z,
                                                const float* __restrict__ y1,
                                                float* __restrict__ eq)
{
    int tid = threadIdx.x;
    int t = blockIdx.x*8 + (tid >> 5);
    int j = tid & 31;
    int deg = counts[t]; if (deg > 128) deg = 128; if (deg < 0) deg = 0;
    float acc = eq[(size_t)t*32 + j];
    const int* bk = bucket + (size_t)t*128;
    if (j < 8) {
        for (int p = 0; p < deg; p++) {
            int s = ei[bk[p] & (EE-1)] & (TT-1);
            acc += z[(size_t)s*16 + j];
        }
    } else {
        int jj = j - 8;
        int kk = jj / 3;
        int mm = jj - kk*3;
        for (int p = 0; p < deg; p++) {
            int e = bk[p] & (EE-1);
            int s = ei[e] & (TT-1);
            acc += z[(size_t)s*16 + 8 + kk] * y1[(size_t)e*3 + mm];
        }
    }
    eq[(size_t)t*32 + j] = acc;
}

// ---------------------------------------------------------------------------
// out = inv * sigmoid(eq@Wg + bg) + (eq@Wes + bes), f32 out.
__global__ __launch_bounds__(256) void k_final(const float* __restrict__ inv,
                                               const float* __restrict__ eq,
                                               const float* __restrict__ Wes,
                                               const float* __restrict__ bes,
                                               const float* __restrict__ Wg,
                                               const float* __restrict__ bg,
                                               float* __restrict__ out)
{
    __shared__ float eql[64];
    int tid = threadIdx.x;
    int row0 = blockIdx.x*2;
    if (tid < 64) eql[tid] = eq[(size_t)row0*32 + tid];
    __syncthreads();
    int rl = tid >> 7, c = tid & 127;
    float a_es = bes[c], a_g = bg[c];
    const float* er = &eql[rl*32];
    #pragma unroll
    for (int jx = 0; jx < 32; jx++) {
        float v = er[jx];
        a_es = fmaf(v, Wes[jx*128 + c], a_es);
        a_g  = fmaf(v, Wg [jx*128 + c], a_g);
    }
    float g = 1.f / (1.f + __expf(-a_g));
    float r = inv[(size_t)(row0 + rl)*128 + c] * g + a_es;
    out[(size_t)(row0 + rl)*128 + c] = r;
}

// ---------------------------------------------------------------------------
extern "C" void kernel_launch(void* const* d_in, const int* in_sizes, int n_in,
                              void* d_out, int out_size, void* d_ws, size_t ws_size,
                              hipStream_t stream)
{
    // Locate edge_index by its unique element count 2*E (robust to adj_mask slot).
    int p = 1;
    while (p < n_in && in_sizes[p] != 2*EE) p++;
    if (p >= n_in) p = 2;

    const size_t M = (size_t)TT*CC;
    const size_t NEED_WORDS = 4*M + (size_t)TT*16 + (size_t)TT*32 + 256 + TT;
    if (ws_size < NEED_WORDS*4) {
        float code = 1000.f + (float)(ws_size >> 20);
        k_diag<<<(out_size + 255)/256, 256, 0, stream>>>((float*)d_out, out_size, code);
        return;
    }

    const float* X   = (const float*)d_in[0];
    const int*   ei  = (const int*)  d_in[p];      // edge_index (2,E) int32
    const float* ev  = (const float*)d_in[p+1];    // edge_vectors (E,3)
    // d_in[p+2] batch_mapping: identity flattening, ignored.
    const int wb = p + 3;
    const float* Wq  = (const float*)d_in[wb+0];  const float* bq = (const float*)d_in[wb+1];
    const float* Wk  = (const float*)d_in[wb+2];  const float* bk = (const float*)d_in[wb+3];
    const float* Wv  = (const float*)d_in[wb+4];  const float* bv = (const float*)d_in[wb+5];
    const float* Wf  = (const float*)d_in[wb+6];  const float* bf_= (const float*)d_in[wb+7];
    const float* g0  = (const float*)d_in[wb+8];  const float* b0 = (const float*)d_in[wb+9];
    const float* g1  = (const float*)d_in[wb+10]; const float* b1 = (const float*)d_in[wb+11];
    const float* Wc  = (const float*)d_in[wb+12]; const float* bc = (const float*)d_in[wb+13];
    const float* W1  = (const float*)d_in[wb+14];
    const float* Wr0 = (const float*)d_in[wb+15];
    const float* Wr1 = (const float*)d_in[wb+16];
    const float* Wr2 = (const float*)d_in[wb+17];
    const float* W20 = (const float*)d_in[wb+18];
    const float* W21 = (const float*)d_in[wb+19];
    const float* Wsc = (const float*)d_in[wb+20];
    const float* Wes = (const float*)d_in[wb+21]; const float* bes = (const float*)d_in[wb+22];
    const float* Wg  = (const float*)d_in[wb+23]; const float* bg  = (const float*)d_in[wb+24];

    float* ws   = (float*)d_ws;
    float* A_   = ws;            // qb -> o_ln -> bucket (ints)
    float* B_   = ws + M;        // kb -> xe -> y1
    float* C_   = ws + 2*M;      // vb -> x1
    float* D_   = ws + 3*M;      // attn -> inv
    float* z    = ws + 4*M;
    float* eq   = z + (size_t)TT*16;
    float* w    = eq + (size_t)TT*32;
    int*   counts = (int*)(w + 256);   // TT ints
    int*   bucket = (int*)A_;          // T*128 ints (qb dead by then)
    float* y1     = B_;                // E*3 (xe dead by then)

    k_compute_w<<<1, 256, 0, stream>>>(Wr0, Wr1, Wr2, w);

    k_gemm<1><<<TT/32, 256, 0, stream>>>(X, Wq, bq, A_, 1.f);
    k_gemm<1><<<TT/32, 256, 0, stream>>>(X, Wk, bk, B_, 1.f);
    k_gemm<1><<<TT/32, 256, 0, stream>>>(X, Wv, bv, C_, 1.f);

    k_attn<<<BB*HH*2, 256, 0, stream>>>(A_, B_, C_, D_);
    k_ln0<<<TT/2, 256, 0, stream>>>(D_, g0, b0, A_);              // o_ln -> A_
    k_ff_ln<<<TT/32, 256, 0, stream>>>(A_, Wf, bf_, g1, b1, D_);  // inv  -> D_

    k_gemm<0><<<TT/32, 256, 0, stream>>>(X, Wc, bc, B_, 1.f);               // xe
    k_gemm<0><<<TT/32, 256, 0, stream>>>(B_, W1, (const float*)nullptr, C_,
                                         0.08838834764831845f);             // x1

    k_z<<<TT/16, 256, 0, stream>>>(C_, W20, W21, w, z);
    k_xsc<<<TT/8, 256, 0, stream>>>(X, Wsc, eq);
    k_y1<<<EE/256, 256, 0, stream>>>(ev, y1);

    hipMemsetAsync(counts, 0, TT*sizeof(int), stream);
    k_bucket<<<EE/256, 256, 0, stream>>>(ei, counts, bucket);
    k_gather<<<TT/8, 256, 0, stream>>>(ei, counts, bucket, z, y1, eq);

    k_final<<<TT/2, 256, 0, stream>>>(D_, eq, Wes, bes, Wg, bg, (float*)d_out);
}

// Round 7
// 452.891 us; speedup vs baseline: 1.1215x; 1.1215x over previous
//
#include <hip/hip_runtime.h>
#include <hip/hip_bf16.h>

// Problem constants (fixed by setup_inputs)
#define BB 16
#define NN 512
#define CC 128
#define HH 8
#define DHD 16
#define TT 8192      // B*N
#define EE 262144    // T*DEG
#define RWD 64

// ---------------------------------------------------------------------------
__global__ void k_diag(float* __restrict__ out, int n, float code)
{
    int i = blockIdx.x*256 + threadIdx.x;
    if (i < n) out[i] = (i == 0) ? code : 0.f;
}

// ---------------------------------------------------------------------------
// w = silu(silu(ones@Wr0) @ Wr1/8) @ Wr2/8   (edge-independent: emb is all-1)
__global__ void k_compute_w(const float* __restrict__ Wr0, const float* __restrict__ Wr1,
                            const float* __restrict__ Wr2, float* __restrict__ w)
{
    __shared__ float h0[RWD], h1[RWD];
    int tid = threadIdx.x;
    if (tid < RWD) { float x = Wr0[tid]; h0[tid] = x / (1.f + __expf(-x)); }
    __syncthreads();
    if (tid < RWD) {
        float s = 0.f;
        for (int i = 0; i < RWD; i++) s += h0[i] * Wr1[i*RWD + tid];
        s *= 0.125f;
        h1[tid] = s / (1.f + __expf(-s));
    }
    __syncthreads();
    {
        float s = 0.f;
        for (int i = 0; i < RWD; i++) s += h1[i] * Wr2[i*2*CC + tid];
        w[tid] = s * 0.125f;
    }
}

// ---------------------------------------------------------------------------
// Wcc = Wc @ W1 / sqrt(C)  (128x128), bcc = bc @ W1 / sqrt(C)  (128)
__global__ void k_prepA(const float* __restrict__ Wc, const float* __restrict__ W1,
                        const float* __restrict__ bc,
                        float* __restrict__ Wcc, float* __restrict__ bcc)
{
    const float SC = 0.08838834764831845f;  // 1/sqrt(128)
    if (blockIdx.x == 64) {
        int c = threadIdx.x;
        if (c < 128) {
            float a = 0.f;
            for (int d = 0; d < 128; d++) a = fmaf(bc[d], W1[d*128 + c], a);
            bcc[c] = a * SC;
        }
        return;
    }
    int idx = blockIdx.x*256 + threadIdx.x;
    int i = idx >> 7, c = idx & 127;
    float a = 0.f;
    for (int d = 0; d < 128; d++) a = fmaf(Wc[i*128 + d], W1[d*128 + c], a);
    Wcc[idx] = a * SC;
}

// ---------------------------------------------------------------------------
// W24[i][j]: j<16 -> Weff = Wcc @ Wz (Wz folds w0/w1*W20/W21*1/sqrt(C*10));
//            j in 16..23 -> Wsc[:,j-16]/sqrt(C).  beff[j] = bcc @ Wz (0 for j>=16).
__global__ void k_prepB(const float* __restrict__ Wcc, const float* __restrict__ bcc,
                        const float* __restrict__ w,
                        const float* __restrict__ W20, const float* __restrict__ W21,
                        const float* __restrict__ Wsc,
                        float* __restrict__ W24, float* __restrict__ beff)
{
    const float SCALE_Z = 0.027950849718747372f;  // 1/sqrt(128*10)
    const float SC      = 0.08838834764831845f;   // 1/sqrt(128)
    int idx = blockIdx.x*256 + threadIdx.x;
    if (idx < 3072) {
        int i = idx / 24, j = idx - (idx/24)*24;
        float a = 0.f;
        if (j < 16) {
            for (int c = 0; c < 128; c++) {
                float wz = (j < 8) ? W20[c*8 + j]*w[c] : W21[c*8 + (j-8)]*w[128 + c];
                a = fmaf(Wcc[i*128 + c], wz, a);
            }
            a *= SCALE_Z;
        } else {
            a = Wsc[i*8 + (j-16)] * SC;
        }
        W24[idx] = a;
    } else if (idx < 3096) {
        int j = idx - 3072;
        float a = 0.f;
        if (j < 16) {
            for (int c = 0; c < 128; c++) {
                float wz = (j < 8) ? W20[c*8 + j]*w[c] : W21[c*8 + (j-8)]*w[128 + c];
                a = fmaf(bcc[c], wz, a);
            }
            a *= SCALE_Z;
        }
        beff[j] = a;
    }
}

// ---------------------------------------------------------------------------
// Fused QKV: (32 rows)x(128 k) tile staged once; 3 weight loops; scatter (B,H,N,16).
__global__ __launch_bounds__(512) void k_qkv(const float* __restrict__ X,
    const float* __restrict__ Wq, const float* __restrict__ bq,
    const float* __restrict__ Wk, const float* __restrict__ bk,
    const float* __restrict__ Wv, const float* __restrict__ bv,
    float* __restrict__ qb, float* __restrict__ kb, float* __restrict__ vb)
{
    __shared__ float a_lds[128][36];   // X^T tile [k][r]
    const int tid  = threadIdx.x;
    const int row0 = blockIdx.x * 32;

    const float4* X4 = (const float4*)(X + (size_t)row0*128);
    for (int fid = tid; fid < 1024; fid += 512) {
        int r = fid >> 5, k4 = (fid & 31) << 2;
        float4 v = X4[(r*128 + k4) >> 2];
        a_lds[k4+0][r] = v.x; a_lds[k4+1][r] = v.y;
        a_lds[k4+2][r] = v.z; a_lds[k4+3][r] = v.w;
    }
    __syncthreads();

    const int c  = tid & 127;
    const int q4 = tid >> 7;          // 0..3 -> rows q4*8 .. q4*8+7
    const float* Ws[3]  = {Wq, Wk, Wv};
    const float* bsx[3] = {bq, bk, bv};
    float* outs[3] = {qb, kb, vb};

    #pragma unroll
    for (int m = 0; m < 3; m++) {
        float acc[8];
        #pragma unroll
        for (int i = 0; i < 8; i++) acc[i] = 0.f;
        const float* bp = Ws[m] + c;
        for (int k = 0; k < 128; k++) {
            float b = bp[k*128];
            const float* ap = &a_lds[k][q4*8];
            #pragma unroll
            for (int i = 0; i < 8; i++) acc[i] = fmaf(ap[i], b, acc[i]);
        }
        float bia = bsx[m][c];
        float* op = outs[m];
        #pragma unroll
        for (int i = 0; i < 8; i++) {
            int r = row0 + q4*8 + i;
            int b_ = r >> 9, n_ = r & 511, h_ = c >> 4, d_ = c & 15;
            op[(((size_t)(b_*HH + h_)*NN + n_)*DHD) + d_] = acc[i] + bia;
        }
    }
}

// ---------------------------------------------------------------------------
// Attention: 4 blocks per (b,h); block = 128 query rows; threads (row, jhalf).
// Each (row,jh) does online softmax over 256 keys; 2-way merge via dead K-LDS.
__global__ __launch_bounds__(256) void k_attn(const float* __restrict__ qb,
                                              const float* __restrict__ kb,
                                              const float* __restrict__ vb,
                                              float* __restrict__ attn)
{
    __shared__ float k_lds[8192];
    __shared__ float v_lds[8192];
    int bh   = blockIdx.x >> 2;
    int tile = blockIdx.x & 3;
    const float4* kp = (const float4*)(kb + (size_t)bh*8192);
    const float4* vp = (const float4*)(vb + (size_t)bh*8192);
    float4* kl4 = (float4*)k_lds;
    float4* vl4 = (float4*)v_lds;
    for (int i = threadIdx.x; i < 2048; i += 256) { kl4[i] = kp[i]; vl4[i] = vp[i]; }

    int r  = threadIdx.x & 127;
    int jh = threadIdx.x >> 7;
    int n  = tile*128 + r;
    float q[16];
    const float4* qp = (const float4*)(qb + ((size_t)bh*512 + n)*16);
    #pragma unroll
    for (int i = 0; i < 4; i++) {
        float4 v = qp[i];
        q[i*4+0] = v.x; q[i*4+1] = v.y; q[i*4+2] = v.z; q[i*4+3] = v.w;
    }
    __syncthreads();

    float m = -1e30f, l = 0.f, o[16];
    #pragma unroll
    for (int d = 0; d < 16; d++) o[d] = 0.f;

    int j0base = jh*256;
    for (int j0 = j0base; j0 < j0base + 256; j0 += 16) {
        float s[16];
        float cmax = -1e30f;
        #pragma unroll
        for (int jj = 0; jj < 16; jj++) {
            const float* kr = &k_lds[(j0 + jj)*16];
            float a = 0.f;
            #pragma unroll
            for (int d = 0; d < 16; d++) a = fmaf(q[d], kr[d], a);
            s[jj] = a * 0.25f;               // 1/sqrt(16)
            cmax = fmaxf(cmax, s[jj]);
        }
        float mn = fmaxf(m, cmax);
        float scale = __expf(m - mn);
        l *= scale;
        #pragma unroll
        for (int d = 0; d < 16; d++) o[d] *= scale;
        #pragma unroll
        for (int jj = 0; jj < 16; jj++) {
            float p = __expf(s[jj] - mn);
            l += p;
            const float* vr = &v_lds[(j0 + jj)*16];
            #pragma unroll
            for (int d = 0; d < 16; d++) o[d] = fmaf(p, vr[d], o[d]);
        }
        m = mn;
    }
    __syncthreads();                 // K-LDS now dead; reuse as merge scratch
    float* scr = k_lds;
    if (jh == 1) {
        scr[r*18 + 0] = m;
        scr[r*18 + 1] = l;
        #pragma unroll
        for (int d = 0; d < 16; d++) scr[r*18 + 2 + d] = o[d];
    }
    __syncthreads();
    if (jh == 0) {
        float m1 = scr[r*18], l1 = scr[r*18 + 1];
        float mm = fmaxf(m, m1);
        float e0 = __expf(m - mm), e1 = __expf(m1 - mm);
        float invl = 1.f / (l*e0 + l1*e1);
        int b_ = bh >> 3, h_ = bh & 7;
        float4* op = (float4*)(attn + ((size_t)(b_*512 + n))*128 + h_*16);
        #pragma unroll
        for (int i = 0; i < 4; i++) {
            float4 v;
            v.x = q[i*4+0] + (o[i*4+0]*e0 + scr[r*18+2+i*4+0]*e1)*invl;
            v.y = q[i*4+1] + (o[i*4+1]*e0 + scr[r*18+2+i*4+1]*e1)*invl;
            v.z = q[i*4+2] + (o[i*4+2]*e0 + scr[r*18+2+i*4+2]*e1)*invl;
            v.w = q[i*4+3] + (o[i*4+3]*e0 + scr[r*18+2+i*4+3]*e1)*invl;
            op[i] = v;
        }
    }
}

// ---------------------------------------------------------------------------
// Fused: o_ln = LN0(o); y = o_ln + relu(o_ln@Wf + bf); out = LN1(y). In-place OK.
__global__ __launch_bounds__(256) void k_ffln(const float* __restrict__ A,
                                              const float* __restrict__ g0,
                                              const float* __restrict__ b0,
                                              const float* __restrict__ Wf,
                                              const float* __restrict__ bfp,
                                              const float* __restrict__ g1,
                                              const float* __restrict__ b1,
                                              float* __restrict__ out)
{
    __shared__ float a_lds[128][36];   // o^T then o_ln^T
    __shared__ float y_lds[32][129];
    __shared__ float red[32][8][2];
    __shared__ float mu_s[32], rs_s[32];
    const int tid  = threadIdx.x;
    const int row0 = blockIdx.x * 32;

    const float4* A4 = (const float4*)(A + (size_t)row0*128);
    for (int fid = tid; fid < 1024; fid += 256) {
        int r = fid >> 5, k4 = (fid & 31) << 2;
        float4 v = A4[(r*128 + k4) >> 2];
        a_lds[k4+0][r] = v.x; a_lds[k4+1][r] = v.y;
        a_lds[k4+2][r] = v.z; a_lds[k4+3][r] = v.w;
    }
    __syncthreads();

    // LN0 stats
    int rr = tid >> 3, seg = tid & 7;
    {
        float s1 = 0.f, s2 = 0.f;
        #pragma unroll
        for (int i = 0; i < 16; i++) {
            float v = a_lds[seg*16 + i][rr];
            s1 += v; s2 += v*v;
        }
        red[rr][seg][0] = s1; red[rr][seg][1] = s2;
    }
    __syncthreads();
    if (seg == 0) {
        float a1 = 0.f, a2 = 0.f;
        #pragma unroll
        for (int s = 0; s < 8; s++) { a1 += red[rr][s][0]; a2 += red[rr][s][1]; }
        float mu = a1 * (1.f/128.f);
        float var = fmaxf(a2 * (1.f/128.f) - mu*mu, 0.f);
        mu_s[rr] = mu; rs_s[rr] = rsqrtf(var + 1e-5f);
    }
    __syncthreads();
    {
        float mu = mu_s[rr], rs = rs_s[rr];
        #pragma unroll
        for (int i = 0; i < 16; i++) {
            int k = seg*16 + i;
            float v = a_lds[k][rr];
            a_lds[k][rr] = (v - mu)*rs*g0[k] + b0[k];
        }
    }
    __syncthreads();

    // FF + residual
    const int c    = tid & 127;
    const int half = tid >> 7;
    float acc[16];
    #pragma unroll
    for (int i = 0; i < 16; i++) acc[i] = 0.f;
    const float* bp = Wf + c;
    for (int k = 0; k < 128; k++) {
        float b = bp[k*128];
        const float* ap = &a_lds[k][half*16];
        #pragma unroll
        for (int i = 0; i < 16; i++) acc[i] = fmaf(ap[i], b, acc[i]);
    }
    float bia = bfp[c];
    #pragma unroll
    for (int i = 0; i < 16; i++) {
        int rl = half*16 + i;
        float oln = a_lds[c][rl];
        y_lds[rl][c] = oln + fmaxf(acc[i] + bia, 0.f);
    }
    __syncthreads();

    // LN1 stats
    {
        float s1 = 0.f, s2 = 0.f;
        for (int c2 = seg*16; c2 < seg*16 + 16; c2++) {
            float v = y_lds[rr][c2];
            s1 += v; s2 += v*v;
        }
        red[rr][seg][0] = s1; red[rr][seg][1] = s2;
    }
    __syncthreads();
    if (seg == 0) {
        float a1 = 0.f, a2 = 0.f;
        #pragma unroll
        for (int s = 0; s < 8; s++) { a1 += red[rr][s][0]; a2 += red[rr][s][1]; }
        float mu = a1 * (1.f/128.f);
        float var = fmaxf(a2 * (1.f/128.f) - mu*mu, 0.f);
        mu_s[rr] = mu; rs_s[rr] = rsqrtf(var + 1e-5f);
    }
    __syncthreads();
    float g = g1[c], bb = b1[c];
    #pragma unroll
    for (int i = 0; i < 16; i++) {
        int rl = half*16 + i;
        float v = y_lds[rl][c];
        out[(size_t)(row0 + rl)*128 + c] = (v - mu_s[rl])*rs_s[rl]*g + bb;
    }
}

// ---------------------------------------------------------------------------
// z[t][0..15] = X[t]@Weff + beff; eq[t][0..7] = X[t]@WscScaled; eq[t][8..31]=0.
__global__ __launch_bounds__(256) void k_zeq(const float* __restrict__ X,
                                             const float* __restrict__ W24,
                                             const float* __restrict__ beff,
                                             float* __restrict__ z,
                                             float* __restrict__ eq)
{
    __shared__ float a_lds[128][36];
    __shared__ float w_lds[128*24];
    __shared__ float be[24];
    int tid = threadIdx.x;
    int row0 = blockIdx.x * 32;
    for (int idx = tid; idx < 3072; idx += 256) w_lds[idx] = W24[idx];
    if (tid < 24) be[tid] = beff[tid];
    const float4* X4 = (const float4*)(X + (size_t)row0*128);
    for (int fid = tid; fid < 1024; fid += 256) {
        int r = fid >> 5, k4 = (fid & 31) << 2;
        float4 v = X4[(r*128 + k4) >> 2];
        a_lds[k4+0][r] = v.x; a_lds[k4+1][r] = v.y;
        a_lds[k4+2][r] = v.z; a_lds[k4+3][r] = v.w;
    }
    __syncthreads();
    int r = tid >> 3, seg = tid & 7;
    float a0 = be[seg], a1 = be[seg+8], a2 = 0.f;
    for (int k = 0; k < 128; k++) {
        float xv = a_lds[k][r];
        a0 = fmaf(xv, w_lds[k*24 + seg],      a0);
        a1 = fmaf(xv, w_lds[k*24 + seg + 8],  a1);
        a2 = fmaf(xv, w_lds[k*24 + seg + 16], a2);
    }
    size_t t = row0 + r;
    z[t*16 + seg]     = a0;
    z[t*16 + seg + 8] = a1;
    eq[t*32 + seg]    = a2;
    for (int idx = tid; idx < 768; idx += 256) {
        int rr2 = idx / 24, jj = 8 + (idx - (idx/24)*24);
        eq[(size_t)(row0 + rr2)*32 + jj] = 0.f;
    }
}

// ---------------------------------------------------------------------------
// Per-edge: Y1 + receiver bucketing (stores snd and edge id directly).
__global__ void k_edge(const int* __restrict__ ei, const float* __restrict__ ev,
                       int* __restrict__ counts, int* __restrict__ bucket_s,
                       int* __restrict__ bucket_e, float* __restrict__ y1)
{
    int e = blockIdx.x*256 + threadIdx.x;
    float x = ev[e*3], y = ev[e*3+1], zz = ev[e*3+2];
    float nrm = sqrtf(x*x + y*y + zz*zz);
    float inv = 1.f / fmaxf(nrm, 1e-12f);
    const float s3 = 1.7320508075688772f;
    y1[e*3 + 0] = s3 * y  * inv;
    y1[e*3 + 1] = s3 * zz * inv;
    y1[e*3 + 2] = s3 * x  * inv;
    int s = ei[e]      & (TT-1);
    int t = ei[EE + e] & (TT-1);
    int pos = atomicAdd(&counts[t], 1);
    if (pos < 128) {
        bucket_s[(size_t)t*128 + pos] = s;
        bucket_e[(size_t)t*128 + pos] = e;
    }
}

// ---------------------------------------------------------------------------
__global__ __launch_bounds__(256) void k_gather(const int* __restrict__ counts,
                                                const int* __restrict__ bucket_s,
                                                const int* __restrict__ bucket_e,
                                                const float* __restrict__ z,
                                                const float* __restrict__ y1,
                                                float* __restrict__ eq)
{
    int tid = threadIdx.x;
    int t = blockIdx.x*8 + (tid >> 5);
    int j = tid & 31;
    int deg = counts[t]; if (deg > 128) deg = 128; if (deg < 0) deg = 0;
    float acc = eq[(size_t)t*32 + j];
    const int* bs = bucket_s + (size_t)t*128;
    const int* be = bucket_e + (size_t)t*128;
    if (j < 8) {
        for (int p = 0; p < deg; p++) {
            int s = bs[p];
            acc += z[(size_t)s*16 + j];
        }
    } else {
        int jj = j - 8;
        int kk = jj / 3;
        int mm = jj - kk*3;
        for (int p = 0; p < deg; p++) {
            int s = bs[p];
            int e = be[p];
            acc += z[(size_t)s*16 + 8 + kk] * y1[(size_t)e*3 + mm];
        }
    }
    eq[(size_t)t*32 + j] = acc;
}

// ---------------------------------------------------------------------------
// out = inv * sigmoid(eq@Wg + bg) + (eq@Wes + bes), f32 out.
__global__ __launch_bounds__(256) void k_final(const float* __restrict__ inv,
                                               const float* __restrict__ eq,
                                               const float* __restrict__ Wes,
                                               const float* __restrict__ bes,
                                               const float* __restrict__ Wg,
                                               const float* __restrict__ bg,
                                               float* __restrict__ out)
{
    __shared__ float eql[64];
    int tid = threadIdx.x;
    int row0 = blockIdx.x*2;
    if (tid < 64) eql[tid] = eq[(size_t)row0*32 + tid];
    __syncthreads();
    int rl = tid >> 7, c = tid & 127;
    float a_es = bes[c], a_g = bg[c];
    const float* er = &eql[rl*32];
    #pragma unroll
    for (int jx = 0; jx < 32; jx++) {
        float v = er[jx];
        a_es = fmaf(v, Wes[jx*128 + c], a_es);
        a_g  = fmaf(v, Wg [jx*128 + c], a_g);
    }
    float g = 1.f / (1.f + __expf(-a_g));
    out[(size_t)(row0 + rl)*128 + c] = inv[(size_t)(row0 + rl)*128 + c] * g + a_es;
}

// ---------------------------------------------------------------------------
extern "C" void kernel_launch(void* const* d_in, const int* in_sizes, int n_in,
                              void* d_out, int out_size, void* d_ws, size_t ws_size,
                              hipStream_t stream)
{
    int p = 1;
    while (p < n_in && in_sizes[p] != 2*EE) p++;
    if (p >= n_in) p = 2;

    const size_t M = (size_t)TT*CC;  // 1,048,576 words
    const size_t NEED_WORDS = 4*M + (size_t)TT*16 + (size_t)TT*32 + 256
                              + 16384 + 128 + 3072 + 32 + TT;
    if (ws_size < NEED_WORDS*4) {
        float code = 1000.f + (float)(ws_size >> 20);
        k_diag<<<(out_size + 255)/256, 256, 0, stream>>>((float*)d_out, out_size, code);
        return;
    }

    const float* X   = (const float*)d_in[0];
    const int*   ei  = (const int*)  d_in[p];
    const float* ev  = (const float*)d_in[p+1];
    const int wb = p + 3;
    const float* Wq  = (const float*)d_in[wb+0];  const float* bq = (const float*)d_in[wb+1];
    const float* Wk  = (const float*)d_in[wb+2];  const float* bk = (const float*)d_in[wb+3];
    const float* Wv  = (const float*)d_in[wb+4];  const float* bv = (const float*)d_in[wb+5];
    const float* Wf  = (const float*)d_in[wb+6];  const float* bf_= (const float*)d_in[wb+7];
    const float* g0  = (const float*)d_in[wb+8];  const float* b0 = (const float*)d_in[wb+9];
    const float* g1  = (const float*)d_in[wb+10]; const float* b1 = (const float*)d_in[wb+11];
    const float* Wc  = (const float*)d_in[wb+12]; const float* bc = (const float*)d_in[wb+13];
    const float* W1  = (const float*)d_in[wb+14];
    const float* Wr0 = (const float*)d_in[wb+15];
    const float* Wr1 = (const float*)d_in[wb+16];
    const float* Wr2 = (const float*)d_in[wb+17];
    const float* W20 = (const float*)d_in[wb+18];
    const float* W21 = (const float*)d_in[wb+19];
    const float* Wsc = (const float*)d_in[wb+20];
    const float* Wes = (const float*)d_in[wb+21]; const float* bes = (const float*)d_in[wb+22];
    const float* Wg  = (const float*)d_in[wb+23]; const float* bg  = (const float*)d_in[wb+24];

    float* ws   = (float*)d_ws;
    float* A_   = ws;            // qb  -> bucket_s (ints)
    float* B_   = ws + M;        // kb  -> y1
    float* C_   = ws + 2*M;      // vb  -> bucket_e (ints)
    float* D_   = ws + 3*M;      // o   -> inv (in-place ffln)
    float* z    = ws + 4*M;                     // T*16
    float* eq   = z + (size_t)TT*16;            // T*32
    float* w    = eq + (size_t)TT*32;           // 256
    float* Wcc  = w + 256;                      // 16384
    float* bcc  = Wcc + 16384;                  // 128
    float* W24  = bcc + 128;                    // 3072
    float* beff = W24 + 3072;                   // 32
    int*   counts   = (int*)(beff + 32);        // TT
    int*   bucket_s = (int*)A_;
    int*   bucket_e = (int*)C_;
    float* y1       = B_;

    k_compute_w<<<1, 256, 0, stream>>>(Wr0, Wr1, Wr2, w);
    k_prepA<<<65, 256, 0, stream>>>(Wc, W1, bc, Wcc, bcc);
    k_prepB<<<13, 256, 0, stream>>>(Wcc, bcc, w, W20, W21, Wsc, W24, beff);

    k_qkv<<<TT/32, 512, 0, stream>>>(X, Wq, bq, Wk, bk, Wv, bv, A_, B_, C_);
    k_attn<<<BB*HH*4, 256, 0, stream>>>(A_, B_, C_, D_);
    k_ffln<<<TT/32, 256, 0, stream>>>(D_, g0, b0, Wf, bf_, g1, b1, D_);

    k_zeq<<<TT/32, 256, 0, stream>>>(X, W24, beff, z, eq);

    hipMemsetAsync(counts, 0, TT*sizeof(int), stream);
    k_edge<<<EE/256, 256, 0, stream>>>(ei, ev, counts, bucket_s, bucket_e, y1);
    k_gather<<<TT/8, 256, 0, stream>>>(counts, bucket_s, bucket_e, z, y1, eq);

    k_final<<<TT/2, 256, 0, stream>>>(D_, eq, Wes, bes, Wg, bg, (float*)d_out);
}